// Round 11
// baseline (346.682 us; speedup 1.0000x reference)
//
#include <hip/hip_runtime.h>

// LIF layer: B=64, T=256, P=1024, D=1024. reference ignores prv_voltage.
// d_out = [voltage (B*T*D fp32) | spikes (B*T*D fp32)].
//
// NUMERICS ARE LOCKED (R10 passed bitwise): currents[row,d] =
//   (asc-p sum over active p in [0,512)) + (asc-p sum over [512,1024)),
// all f32; scan = f32 separate mul-then-add, >=1.0, reset-to-zero.
// Any optimization must preserve these exact sums. +0.0f adds are bitwise
// identity (accumulators can never be -0.0), enabling padded batch slots.
//
// R11 perf change: K1 was L2-gather-bound at 18.3 TB/s (53% of L2 peak) —
// the serial ctz->load->add chain left ~1 outstanding load per wave.
// Now: extract up to 8 set bits per iteration (scalar/uniform ops), issue
// 8 concurrent dwordx4 loads, then accumulate in ascending order with
// invalid slots contributing exact +0.0f. MLP ~6x -> target L2 peak.

#define LIF_B 64
#define LIF_T 256
#define LIF_P 1024
#define LIF_D 1024
#define LIF_N ((size_t)LIF_B * LIF_T * LIF_D)

__global__ __launch_bounds__(256) void lif_currents_kernel(
    const float* __restrict__ spikes,   // (B*T, P)
    const float* __restrict__ W,        // (P, D)
    float* __restrict__ cur_out)        // (B*T, D) — voltage region of d_out
{
    const int row  = blockIdx.x;          // 0 .. B*T-1
    const int lane = threadIdx.x & 63;
    const int wave = threadIdx.x >> 6;    // 4 waves x 256 d-columns
    const int dbase = wave << 8;

    const float* srow = spikes + (size_t)row * LIF_P;
    const float* wcol = W + dbase + (lane << 2);   // this lane's 4 columns

    // Two K-panels: p in [0,512), [512,1024)  (chunks 0..7, 8..15)
    float a0x=0.f,a0y=0.f,a0z=0.f,a0w=0.f;
    float a1x=0.f,a1y=0.f,a1z=0.f,a1w=0.f;

    #define LIF_PANEL(J0, J1, AX, AY, AZ, AW)                                    \
    for (int j = (J0); j < (J1); ++j) {                                          \
        const float sv = srow[(j << 6) + lane];                                  \
        unsigned long long mm = __ballot(sv != 0.0f);                            \
        const int pbase = j << 6;                                                \
        while (mm) {                                                             \
            /* batch-extract up to 8 ascending set bits (wave-uniform) */        \
            const int q0 = pbase + __builtin_ctzll(mm); mm &= (mm - 1);          \
            const bool h1 = (mm != 0);                                           \
            const int q1 = h1 ? pbase + __builtin_ctzll(mm) : q0; mm &= (mm-1);  \
            const bool h2 = (mm != 0);                                           \
            const int q2 = h2 ? pbase + __builtin_ctzll(mm) : q0; mm &= (mm-1);  \
            const bool h3 = (mm != 0);                                           \
            const int q3 = h3 ? pbase + __builtin_ctzll(mm) : q0; mm &= (mm-1);  \
            const bool h4 = (mm != 0);                                           \
            const int q4 = h4 ? pbase + __builtin_ctzll(mm) : q0; mm &= (mm-1);  \
            const bool h5 = (mm != 0);                                           \
            const int q5 = h5 ? pbase + __builtin_ctzll(mm) : q0; mm &= (mm-1);  \
            const bool h6 = (mm != 0);                                           \
            const int q6 = h6 ? pbase + __builtin_ctzll(mm) : q0; mm &= (mm-1);  \
            const bool h7 = (mm != 0);                                           \
            const int q7 = h7 ? pbase + __builtin_ctzll(mm) : q0; mm &= (mm-1);  \
            /* 8 concurrent 16B loads (slots >count re-load q0, harmless) */     \
            const float4 w0 = *reinterpret_cast<const float4*>(wcol + ((size_t)q0 << 10)); \
            const float4 w1 = *reinterpret_cast<const float4*>(wcol + ((size_t)q1 << 10)); \
            const float4 w2 = *reinterpret_cast<const float4*>(wcol + ((size_t)q2 << 10)); \
            const float4 w3 = *reinterpret_cast<const float4*>(wcol + ((size_t)q3 << 10)); \
            const float4 w4 = *reinterpret_cast<const float4*>(wcol + ((size_t)q4 << 10)); \
            const float4 w5 = *reinterpret_cast<const float4*>(wcol + ((size_t)q5 << 10)); \
            const float4 w6 = *reinterpret_cast<const float4*>(wcol + ((size_t)q6 << 10)); \
            const float4 w7 = *reinterpret_cast<const float4*>(wcol + ((size_t)q7 << 10)); \
            /* ascending accumulation; invalid slots add exact +0.0f */          \
            AX = __fadd_rn(AX, w0.x); AY = __fadd_rn(AY, w0.y);                  \
            AZ = __fadd_rn(AZ, w0.z); AW = __fadd_rn(AW, w0.w);                  \
            AX = __fadd_rn(AX, h1 ? w1.x : 0.0f); AY = __fadd_rn(AY, h1 ? w1.y : 0.0f); \
            AZ = __fadd_rn(AZ, h1 ? w1.z : 0.0f); AW = __fadd_rn(AW, h1 ? w1.w : 0.0f); \
            AX = __fadd_rn(AX, h2 ? w2.x : 0.0f); AY = __fadd_rn(AY, h2 ? w2.y : 0.0f); \
            AZ = __fadd_rn(AZ, h2 ? w2.z : 0.0f); AW = __fadd_rn(AW, h2 ? w2.w : 0.0f); \
            AX = __fadd_rn(AX, h3 ? w3.x : 0.0f); AY = __fadd_rn(AY, h3 ? w3.y : 0.0f); \
            AZ = __fadd_rn(AZ, h3 ? w3.z : 0.0f); AW = __fadd_rn(AW, h3 ? w3.w : 0.0f); \
            AX = __fadd_rn(AX, h4 ? w4.x : 0.0f); AY = __fadd_rn(AY, h4 ? w4.y : 0.0f); \
            AZ = __fadd_rn(AZ, h4 ? w4.z : 0.0f); AW = __fadd_rn(AW, h4 ? w4.w : 0.0f); \
            AX = __fadd_rn(AX, h5 ? w5.x : 0.0f); AY = __fadd_rn(AY, h5 ? w5.y : 0.0f); \
            AZ = __fadd_rn(AZ, h5 ? w5.z : 0.0f); AW = __fadd_rn(AW, h5 ? w5.w : 0.0f); \
            AX = __fadd_rn(AX, h6 ? w6.x : 0.0f); AY = __fadd_rn(AY, h6 ? w6.y : 0.0f); \
            AZ = __fadd_rn(AZ, h6 ? w6.z : 0.0f); AW = __fadd_rn(AW, h6 ? w6.w : 0.0f); \
            AX = __fadd_rn(AX, h7 ? w7.x : 0.0f); AY = __fadd_rn(AY, h7 ? w7.y : 0.0f); \
            AZ = __fadd_rn(AZ, h7 ? w7.z : 0.0f); AW = __fadd_rn(AW, h7 ? w7.w : 0.0f); \
        }                                                                        \
    }

    LIF_PANEL(0, 8,   a0x, a0y, a0z, a0w)   // p in [0, 512)
    LIF_PANEL(8, 16,  a1x, a1y, a1z, a1w)   // p in [512, 1024)
    #undef LIF_PANEL

    // Panel association: P0 + P1, plain f32 add.
    float4 c;
    c.x = __fadd_rn(a0x, a1x);
    c.y = __fadd_rn(a0y, a1y);
    c.z = __fadd_rn(a0z, a1z);
    c.w = __fadd_rn(a0w, a1w);

    *reinterpret_cast<float4*>(cur_out + (size_t)row * LIF_D + dbase + (lane << 2)) = c;
}

__global__ __launch_bounds__(256) void lif_scan_kernel(
    float* __restrict__ voltage,        // in: staged currents, out: v_new
    float* __restrict__ spikes_out)     // out: binary spikes
{
    const int tid = blockIdx.x * 256 + threadIdx.x;   // 0 .. B*D-1
    const int b = tid >> 10;
    const int d = tid & (LIF_D - 1);

    float v = 0.0f;
    const size_t base = ((size_t)b * LIF_T) * LIF_D + d;

    for (int t = 0; t < LIF_T; ++t) {
        const size_t idx = base + (size_t)t * LIF_D;
        const float cur = voltage[idx];                     // staged current
        // numpy scan: separate f32 mul then add (no FMA contraction)
        const float vn = __fadd_rn(__fmul_rn(0.9f, v), cur);
        const bool fired = (vn >= 1.0f);
        voltage[idx]    = vn;                               // pre-reset voltage
        spikes_out[idx] = fired ? 1.0f : 0.0f;
        v = fired ? 0.0f : vn;                              // reset-to-zero
    }
}

extern "C" void kernel_launch(void* const* d_in, const int* in_sizes, int n_in,
                              void* d_out, int out_size, void* d_ws, size_t ws_size,
                              hipStream_t stream) {
    (void)in_sizes; (void)n_in; (void)out_size; (void)d_ws; (void)ws_size;

    // d_in[0] = prv_voltage (UNUSED by reference)
    const float* spikes = (const float*)d_in[1];   // (B,T,P) binary fp32
    const float* W      = (const float*)d_in[2];   // (P,D) fp32

    float* out        = (float*)d_out;
    float* voltage    = out;                       // N floats (stages currents)
    float* spikes_out = out + LIF_N;               // N floats

    lif_currents_kernel<<<LIF_B * LIF_T, 256, 0, stream>>>(spikes, W, voltage);
    lif_scan_kernel<<<(LIF_B * LIF_D) / 256, 256, 0, stream>>>(voltage, spikes_out);
}

// Round 12
// 271.939 us; speedup vs baseline: 1.2748x; 1.2748x over previous
//
#include <hip/hip_runtime.h>

// LIF layer: B=64, T=256, P=1024, D=1024. reference ignores prv_voltage.
// d_out = [voltage (B*T*D fp32) | spikes (B*T*D fp32)].
//
// NUMERICS ARE LOCKED (R10 passed): currents[row,d] =
//   (asc-p f32 sum over active p in [0,512)) + (asc-p f32 sum over [512,1024)),
// scan = f32 separate mul-then-add, >=1.0, reset-to-zero. Any optimization
// must preserve these exact sums bitwise.
//
// R12: R11's cndmask-batch regressed (VALU 2x, +53% HBM from duplicate loads
// + L2 thrash). Clean MLP instead: per block, build the row's ascending
// active-p LIST in LDS once (cooperative ballots + 16-lane prefix), then the
// main loop walks the list 4-at-a-time: 1 broadcast ds_read_b128 -> 4
// distinct concurrent dwordx4 W loads -> 16 in-order adds. No duplicates,
// no per-element conditionals. K2: 4-deep prefetch (loads independent of
// the serial v chain).

#define LIF_B 64
#define LIF_T 256
#define LIF_P 1024
#define LIF_D 1024
#define LIF_N ((size_t)LIF_B * LIF_T * LIF_D)

__global__ __launch_bounds__(256) void lif_currents_kernel(
    const float* __restrict__ spikes,   // (B*T, P)
    const float* __restrict__ W,        // (P, D)
    float* __restrict__ cur_out)        // (B*T, D) — voltage region of d_out
{
    __shared__ unsigned long long smask[16];
    __shared__ int plist[1024];          // panel0 at [0..c0), panel1 at [512..512+c1)
    __shared__ int scnt[2];

    const int row  = blockIdx.x;          // 0 .. B*T-1
    const int tid  = threadIdx.x;
    const int lane = tid & 63;
    const int wave = tid >> 6;            // 4 waves x 256 d-columns
    const int dbase = wave << 8;

    const float* srow = spikes + (size_t)row * LIF_P;
    const float* wcol = W + dbase + (lane << 2);   // this lane's 4 columns

    // Phase 1: cooperative mask build — wave w handles chunks 4w..4w+3.
    for (int jj = 0; jj < 4; ++jj) {
        const int j = (wave << 2) + jj;
        const float sv = srow[(j << 6) + lane];
        const unsigned long long m = __ballot(sv != 0.0f);
        if (lane == 0) smask[j] = m;
    }
    __syncthreads();

    // Phase 2: wave 0, lanes 0..15 build ascending p-lists (one chunk each).
    if (wave == 0) {
        unsigned long long m = (lane < 16) ? smask[lane] : 0ULL;
        const int pc = __popcll(m);
        int s = pc;                       // inclusive prefix within 8-lane group
        for (int d = 1; d < 8; d <<= 1) {
            const int vps = __shfl_up(s, d, 8);
            if ((lane & 7) >= d) s += vps;
        }
        if (lane == 7)  scnt[0] = s;
        if (lane == 15) scnt[1] = s;
        if (lane < 16) {
            int idx = ((lane < 8) ? 0 : 512) + (s - pc);
            const int pb = lane << 6;
            while (m) {
                plist[idx++] = pb + __builtin_ctzll(m);
                m &= (m - 1);
            }
        }
    }
    __syncthreads();

    const int c0 = scnt[0];
    const int c1 = scnt[1];

    float a0x=0.f,a0y=0.f,a0z=0.f,a0w=0.f;
    float a1x=0.f,a1y=0.f,a1z=0.f,a1w=0.f;

    #define LIF_ACC(AX,AY,AZ,AW,WV)                                             \
        AX = __fadd_rn(AX, (WV).x); AY = __fadd_rn(AY, (WV).y);                  \
        AZ = __fadd_rn(AZ, (WV).z); AW = __fadd_rn(AW, (WV).w);

    #define LIF_PANEL(BASE, CNT, AX,AY,AZ,AW)                                    \
    {                                                                            \
        int i = 0;                                                               \
        for (; i + 4 <= (CNT); i += 4) {                                         \
            const int4 ps = *reinterpret_cast<const int4*>(&plist[(BASE) + i]);  \
            const float4 w0 = *reinterpret_cast<const float4*>(wcol + ((size_t)ps.x << 10)); \
            const float4 w1 = *reinterpret_cast<const float4*>(wcol + ((size_t)ps.y << 10)); \
            const float4 w2 = *reinterpret_cast<const float4*>(wcol + ((size_t)ps.z << 10)); \
            const float4 w3 = *reinterpret_cast<const float4*>(wcol + ((size_t)ps.w << 10)); \
            LIF_ACC(AX,AY,AZ,AW, w0) LIF_ACC(AX,AY,AZ,AW, w1)                    \
            LIF_ACC(AX,AY,AZ,AW, w2) LIF_ACC(AX,AY,AZ,AW, w3)                    \
        }                                                                        \
        for (; i < (CNT); ++i) {                                                 \
            const int p = plist[(BASE) + i];                                     \
            const float4 wv = *reinterpret_cast<const float4*>(wcol + ((size_t)p << 10)); \
            LIF_ACC(AX,AY,AZ,AW, wv)                                             \
        }                                                                        \
    }

    LIF_PANEL(0,   c0, a0x,a0y,a0z,a0w)   // p in [0, 512), ascending
    LIF_PANEL(512, c1, a1x,a1y,a1z,a1w)   // p in [512, 1024), ascending
    #undef LIF_PANEL
    #undef LIF_ACC

    // Panel association: P0 + P1, plain f32 add (locked).
    float4 c;
    c.x = __fadd_rn(a0x, a1x);
    c.y = __fadd_rn(a0y, a1y);
    c.z = __fadd_rn(a0z, a1z);
    c.w = __fadd_rn(a0w, a1w);

    *reinterpret_cast<float4*>(cur_out + (size_t)row * LIF_D + dbase + (lane << 2)) = c;
}

__global__ __launch_bounds__(256) void lif_scan_kernel(
    float* __restrict__ voltage,        // in: staged currents, out: v_new
    float* __restrict__ spikes_out)     // out: binary spikes
{
    const int tid = blockIdx.x * 256 + threadIdx.x;   // 0 .. B*D-1
    const int b = tid >> 10;
    const int d = tid & (LIF_D - 1);

    float v = 0.0f;
    const size_t base = ((size_t)b * LIF_T) * LIF_D + d;

    // 4-deep prefetch: current loads don't depend on the serial v chain.
    float p0 = voltage[base + 0*(size_t)LIF_D];
    float p1 = voltage[base + 1*(size_t)LIF_D];
    float p2 = voltage[base + 2*(size_t)LIF_D];
    float p3 = voltage[base + 3*(size_t)LIF_D];

    for (int t = 0; t < LIF_T; t += 4) {
        const float c0 = p0, c1 = p1, c2 = p2, c3 = p3;
        if (t + 4 < LIF_T) {
            p0 = voltage[base + (size_t)(t + 4) * LIF_D];
            p1 = voltage[base + (size_t)(t + 5) * LIF_D];
            p2 = voltage[base + (size_t)(t + 6) * LIF_D];
            p3 = voltage[base + (size_t)(t + 7) * LIF_D];
        }
        const size_t i0 = base + (size_t)t * LIF_D;
        // numpy scan: separate f32 mul then add (no FMA contraction) — locked.
        {
            const float vn = __fadd_rn(__fmul_rn(0.9f, v), c0);
            const bool f = (vn >= 1.0f);
            voltage[i0 + 0*(size_t)LIF_D] = vn;
            spikes_out[i0 + 0*(size_t)LIF_D] = f ? 1.0f : 0.0f;
            v = f ? 0.0f : vn;
        }
        {
            const float vn = __fadd_rn(__fmul_rn(0.9f, v), c1);
            const bool f = (vn >= 1.0f);
            voltage[i0 + 1*(size_t)LIF_D] = vn;
            spikes_out[i0 + 1*(size_t)LIF_D] = f ? 1.0f : 0.0f;
            v = f ? 0.0f : vn;
        }
        {
            const float vn = __fadd_rn(__fmul_rn(0.9f, v), c2);
            const bool f = (vn >= 1.0f);
            voltage[i0 + 2*(size_t)LIF_D] = vn;
            spikes_out[i0 + 2*(size_t)LIF_D] = f ? 1.0f : 0.0f;
            v = f ? 0.0f : vn;
        }
        {
            const float vn = __fadd_rn(__fmul_rn(0.9f, v), c3);
            const bool f = (vn >= 1.0f);
            voltage[i0 + 3*(size_t)LIF_D] = vn;
            spikes_out[i0 + 3*(size_t)LIF_D] = f ? 1.0f : 0.0f;
            v = f ? 0.0f : vn;
        }
    }
}

extern "C" void kernel_launch(void* const* d_in, const int* in_sizes, int n_in,
                              void* d_out, int out_size, void* d_ws, size_t ws_size,
                              hipStream_t stream) {
    (void)in_sizes; (void)n_in; (void)out_size; (void)d_ws; (void)ws_size;

    // d_in[0] = prv_voltage (UNUSED by reference)
    const float* spikes = (const float*)d_in[1];   // (B,T,P) binary fp32
    const float* W      = (const float*)d_in[2];   // (P,D) fp32

    float* out        = (float*)d_out;
    float* voltage    = out;                       // N floats (stages currents)
    float* spikes_out = out + LIF_N;               // N floats

    lif_currents_kernel<<<LIF_B * LIF_T, 256, 0, stream>>>(spikes, W, voltage);
    lif_scan_kernel<<<(LIF_B * LIF_D) / 256, 256, 0, stream>>>(voltage, spikes_out);
}